// Round 20
// baseline (114.398 us; speedup 1.0000x reference)
//
#include <hip/hip_runtime.h>

typedef __attribute__((ext_vector_type(8))) _Float16 half8;
typedef __attribute__((ext_vector_type(4))) _Float16 half4;
typedef __attribute__((ext_vector_type(4))) float f32x4;
typedef __attribute__((ext_vector_type(16))) float f32x16;
typedef __attribute__((ext_vector_type(4))) int int4v;

#define BS 2
#define QLEN 2048
#define DIM 1024
#define NH 16
#define DPH 64
#define MTOT (BS * QLEN)   // 4096
#define LOG2E 1.44269504088896340736f

// counted-vmcnt barrier pair (T4): publish LDS without draining in-flight
// prefetch loads. WAITB: own prev-tile loads done -> barrier -> pin sched.
#define WAITB(N)                                          \
    asm volatile("s_waitcnt vmcnt(" #N ")" ::: "memory"); \
    __builtin_amdgcn_s_barrier();                         \
    __builtin_amdgcn_sched_barrier(0)
#define ENDB()                                            \
    __builtin_amdgcn_sched_barrier(0);                    \
    __builtin_amdgcn_s_barrier()

// ---------------------------------------------------------------------------
// merged fp32 -> fp16 conversion: X then Wq/Wk/Wv/Wo in one grid-stride kernel
// ---------------------------------------------------------------------------
__global__ void cvt_all(const float* __restrict__ x,
                        const float* __restrict__ wq, const float* __restrict__ wk,
                        const float* __restrict__ wv, const float* __restrict__ wo,
                        _Float16* __restrict__ X16,
                        _Float16* __restrict__ Wq16, _Float16* __restrict__ Wk16,
                        _Float16* __restrict__ Wv16, _Float16* __restrict__ Wo16) {
    const int NX = (MTOT * DIM) / 4;        // 1,048,576 float4
    const int NW = (DIM * DIM) / 4;         // 262,144 float4 (pow2 -> shifts)
    const int total = NX + 4 * NW;
    int idx = blockIdx.x * blockDim.x + threadIdx.x;
    int stride = gridDim.x * blockDim.x;
    for (int i = idx; i < total; i += stride) {
        const float* src; _Float16* dst; int off;
        if (i < NX) { src = x; dst = X16; off = i; }
        else {
            int k = i - NX; int which = k / NW; off = k - which * NW;
            src = which == 0 ? wq : which == 1 ? wk : which == 2 ? wv : wo;
            dst = which == 0 ? Wq16 : which == 1 ? Wk16 : which == 2 ? Wv16 : Wo16;
        }
        float4 v = ((const float4*)src)[off];
        half4 o;
        o[0] = (_Float16)v.x; o[1] = (_Float16)v.y;
        o[2] = (_Float16)v.z; o[3] = (_Float16)v.w;
        ((half4*)dst)[off] = o;
    }
}

// ---------------------------------------------------------------------------
__device__ __forceinline__ void gload_lds16(const _Float16* g, _Float16* l) {
    __builtin_amdgcn_global_load_lds(
        (const __attribute__((address_space(1))) void*)g,
        (__attribute__((address_space(3))) void*)l, 16, 0, 0);
}

// ---------------------------------------------------------------------------
// Fused QKV NT-GEMM (R16 best-measured): 128x128 tile, 2-phase dbuf,
// counted-vmcnt raw barriers, 4-chunk XOR swizzle, hoisted pointers, XCD
// grid, LDS-repack coalesced epilogue (z=2 transposed in LDS).
// z=0: Q16 scaled by (1/8)*log2e; z=1: K16 mask-zeroed; z=2: V16T.
// ---------------------------------------------------------------------------
__global__ __launch_bounds__(256) void gemm_qkv(
    const _Float16* __restrict__ A,
    const _Float16* __restrict__ Wq, const _Float16* __restrict__ Wk,
    const _Float16* __restrict__ Wv,
    const float* __restrict__ bq, const float* __restrict__ bk,
    const float* __restrict__ bv, const int* __restrict__ mask,
    _Float16* __restrict__ Qd, _Float16* __restrict__ Kd,
    _Float16* __restrict__ Vd) {
    const int K = 1024;
    __shared__ _Float16 sm[16384];

    // XCD-aware decode (bijective; per-XCD WS ~ L2-resident)
    const int flat = blockIdx.x;             // 0..767
    const int xcd = flat & 7, seq = flat >> 3;
    const int ya = xcd >> 1, nb = xcd & 1;
    const int n_hi = seq & 3;
    const int rem = seq >> 2;                // 0..23
    const int z = rem % 3, y_hi = rem / 3;   // y_hi 0..7
    const int y = y_hi * 4 + ya;             // 0..31
    const int nblk = n_hi * 2 + nb;          // 0..7
    const int m0 = y * 128, n0 = nblk * 128;

    const _Float16* W = (z == 0) ? Wq : (z == 1) ? Wk : Wv;
    const float* bias = (z == 0) ? bq : (z == 1) ? bk : bv;

    const int tid = threadIdx.x, w = tid >> 6, l = tid & 63;
    const int wr = (w >> 1) * 64, wc = (w & 1) * 64;
    const int r = l & 15, g = l >> 4;

    // hoisted stage pointers: slot s = tid + i*256 holds chunk (s&3)^(row&3)
    const _Float16* gA[2];
    const _Float16* gW[2];
    _Float16* dA[2];
    _Float16* dB[2];
#pragma unroll
    for (int i = 0; i < 2; ++i) {
        int s = tid + i * 256, row = s >> 2, pos = s & 3;
        int chunk = pos ^ (row & 3);
        gA[i] = &A[(size_t)(m0 + row) * K + chunk * 8];
        gW[i] = &W[(size_t)(n0 + row) * K + chunk * 8];
        dA[i] = &sm[s * 8];
        dB[i] = &sm[8192 + s * 8];
    }
    auto stageAdv = [&](int bb) {
#pragma unroll
        for (int i = 0; i < 2; ++i) {
            gload_lds16(gA[i], dA[i] + bb * 4096);
            gload_lds16(gW[i], dB[i] + bb * 4096);
            gA[i] += 32;                      // next BK=32 K-slice
            gW[i] += 32;
        }
    };

    // hoisted frag pointers; swizzled read pos = g ^ (r&3) (row-invariant)
    const int fpos = (g ^ (r & 3)) * 8;
    const _Float16* pA[4];
    const _Float16* pB[4];
#pragma unroll
    for (int i = 0; i < 4; ++i) {
        pA[i] = &sm[(wr + i * 16 + r) * 32] + fpos;
        pB[i] = &sm[8192 + (wc + i * 16 + r) * 32] + fpos;
    }

    f32x4 acc[4][4] = {};
    auto compute = [&](int bb) {
        const int boff = bb * 4096;
        half8 af[4], bf[4];
#pragma unroll
        for (int i = 0; i < 4; ++i) {
            af[i] = *(const half8*)(pA[i] + boff);
            bf[i] = *(const half8*)(pB[i] + boff);
        }
#pragma unroll
        for (int i = 0; i < 4; ++i)
#pragma unroll
            for (int j = 0; j < 4; ++j)
                acc[i][j] = __builtin_amdgcn_mfma_f32_16x16x32_f16(
                    af[i], bf[j], acc[i][j], 0, 0, 0);
    };

    // ---- main loop: 32 K-steps, unrolled x2, counted-vmcnt pipeline ----
    stageAdv(0);                 // k0 -> buf0          (4 in flight)
    for (int t = 0; t < 16; ++t) {
        stageAdv(1);             // k(2t+1) -> buf1     (8 in flight)
        WAITB(4);                // k(2t) landed; k(2t+1) stays in flight
        compute(0);
        ENDB();                  // all waves done reading buf0
        stageAdv(0);             // k(2t+2) -> buf0 (t=15: dummy, ws-safe)
        WAITB(4);                // k(2t+1) landed
        compute(1);
        ENDB();
    }
    // drain the dummy tail-stage before reusing LDS for the epilogue
    asm volatile("s_waitcnt vmcnt(0)" ::: "memory");
    __builtin_amdgcn_s_barrier();

    float bv4[4];
#pragma unroll
    for (int j = 0; j < 4; ++j) bv4[j] = bias[n0 + wc + j * 16 + r];

    // ---- epilogue pass 1: acc -> LDS, destination-major, chunk-swizzled ----
    if (z != 2) {
#pragma unroll
        for (int i = 0; i < 4; ++i)
#pragma unroll
            for (int j = 0; j < 4; ++j)
#pragma unroll
                for (int reg = 0; reg < 4; ++reg) {
                    const int m = wr + i * 16 + g * 4 + reg;
                    const int n = wc + j * 16 + r;
                    float v = acc[i][j][reg] + bv4[j];
                    if (z == 0) v *= 0.125f * LOG2E;
                    sm[m * 128 + (((n >> 3) ^ (m & 15)) * 8) + (n & 7)] =
                        (_Float16)v;
                }
    } else {
#pragma unroll
        for (int i = 0; i < 4; ++i)
#pragma unroll
            for (int j = 0; j < 4; ++j)
#pragma unroll
                for (int reg = 0; reg < 4; ++reg) {
                    const int m = wr + i * 16 + g * 4 + reg;
                    const int n = wc + j * 16 + r;
                    float v = acc[i][j][reg] + bv4[j];
                    sm[n * 128 + (((m >> 3) ^ (n & 15)) * 8) + (m & 7)] =
                        (_Float16)v;
                }
    }
    __syncthreads();

    // ---- epilogue pass 2: 8 coalesced half8 stores per thread ----
    const int bb = m0 >> 11;                    // uniform per block
    if (z != 2) {
        _Float16* dst0 = (z == 0) ? Qd : Kd;
        const half8 zz = {};
#pragma unroll
        for (int k = 0; k < 8; ++k) {
            const int c = tid * 8 + k;          // 0..2047
            const int m = c >> 4, cc = c & 15;
            half8 v = *(const half8*)&sm[m * 128 + ((cc ^ (m & 15)) * 8)];
            const int ttl = (m0 + m) & 2047;
            const int h = (n0 >> 6) + (cc >> 3);
            const int d = (cc & 7) * 8;
            if (z == 1 && mask[bb * QLEN + ttl] == 0) v = zz;
            *(half8*)&dst0[(((size_t)(bb * NH + h)) * QLEN + ttl) * DPH + d] = v;
        }
    } else {
#pragma unroll
        for (int k = 0; k < 8; ++k) {
            const int c = tid * 8 + k;
            const int dl = c >> 4, cc = c & 15;
            half8 v = *(const half8*)&sm[dl * 128 + ((cc ^ (dl & 15)) * 8)];
            const int ng = n0 + dl, h = ng >> 6, dg = ng & 63;
            const int tt0 = (m0 & 2047) + cc * 8;
            *(half8*)&Vd[(((size_t)(bb * NH + h)) * DPH + dg) * QLEN + tt0] = v;
        }
    }
}

// ---------------------------------------------------------------------------
// Output GEMM: out = CTX @ Wo^T + bo (fp32). 64x128 tile + hoisted pointers
// + unroll x2 + counted-vmcnt raw barriers (R13 exact — frozen).
// ---------------------------------------------------------------------------
__global__ __launch_bounds__(256) void gemm_out(
    const _Float16* __restrict__ A, const _Float16* __restrict__ W,
    const float* __restrict__ bias, float* __restrict__ out) {
    const int K = 1024;
    __shared__ _Float16 sA[2][64 * 32];
    __shared__ _Float16 sB[2][128 * 32];
    const int m0 = blockIdx.y * 64, n0 = blockIdx.x * 128;
    const int tid = threadIdx.x, w = tid >> 6, l = tid & 63;
    const int wr = (w >> 1) * 32, wc = (w & 1) * 64;
    const int r = l & 15, g = l >> 4;

    // hoisted stage pointers (linear layout)
    const _Float16* gA;
    const _Float16* gB[2];
    _Float16* dA;
    _Float16* dB[2];
    {
        int s = tid, row = s >> 2, seg = (s & 3) * 8;
        gA = &A[(size_t)(m0 + row) * K + seg];
        dA = &sA[0][s * 8];
    }
#pragma unroll
    for (int i = 0; i < 2; ++i) {
        int s = tid + i * 256, row = s >> 2, seg = (s & 3) * 8;
        gB[i] = &W[(size_t)(n0 + row) * K + seg];
        dB[i] = &sB[0][s * 8];
    }
    auto stageAdv = [&](int bb) {
        gload_lds16(gA, dA + bb * 2048);
        gA += 32;
#pragma unroll
        for (int i = 0; i < 2; ++i) {
            gload_lds16(gB[i], dB[i] + bb * 4096);
            gB[i] += 32;
        }
    };

    const _Float16* pA[2];
    const _Float16* pB[4];
#pragma unroll
    for (int i = 0; i < 2; ++i)
        pA[i] = &sA[0][(wr + i * 16 + r) * 32 + g * 8];
#pragma unroll
    for (int j = 0; j < 4; ++j)
        pB[j] = &sB[0][(wc + j * 16 + r) * 32 + g * 8];

    f32x4 acc[2][4] = {};
    auto compute = [&](int bb) {
        half8 af[2], bf[4];
#pragma unroll
        for (int i = 0; i < 2; ++i)
            af[i] = *(const half8*)(pA[i] + bb * 2048);
#pragma unroll
        for (int j = 0; j < 4; ++j)
            bf[j] = *(const half8*)(pB[j] + bb * 4096);
#pragma unroll
        for (int i = 0; i < 2; ++i)
#pragma unroll
            for (int j = 0; j < 4; ++j)
                acc[i][j] = __builtin_amdgcn_mfma_f32_16x16x32_f16(
                    af[i], bf[j], acc[i][j], 0, 0, 0);
    };

    stageAdv(0);
    for (int t = 0; t < 16; ++t) {
        stageAdv(1);
        WAITB(3);
        compute(0);
        ENDB();
        stageAdv(0);             // t=15: dummy, ws-safe
        WAITB(3);
        compute(1);
        ENDB();
    }

    float bv4[4];
#pragma unroll
    for (int j = 0; j < 4; ++j) bv4[j] = bias[n0 + wc + j * 16 + r];
#pragma unroll
    for (int i = 0; i < 2; ++i)
#pragma unroll
        for (int j = 0; j < 4; ++j) {
            const int n = n0 + wc + j * 16 + r;
#pragma unroll
            for (int reg = 0; reg < 4; ++reg) {
                const int m = m0 + wr + i * 16 + g * 4 + reg;
                out[(size_t)m * DIM + n] = acc[i][j][reg] + bv4[j];
            }
        }
}

// ---------------------------------------------------------------------------
// Flash attention v8: 32-key KV tiles -> LDS 36KB -> 4 blocks/CU = 32
// waves/CU (full occupancy; was 2 blocks / 16 waves at 64KB). Same per-wave
// work per 64 keys (16 reads, 16 MFMAs), finer-grained; counted-vmcnt
// pipeline (WAITB(2): 1 K + 1 V gload/wave/tile). V rows now 64B: swizzle
// key (row>>1)&3 (4-way bank floor preserved both sides, rule #21).
// ---------------------------------------------------------------------------
__global__ __launch_bounds__(512) void attn_kernel(
    const _Float16* __restrict__ Qg, const _Float16* __restrict__ Kg,
    const _Float16* __restrict__ Vg, _Float16* __restrict__ ctx) {
    __shared__ __align__(16) char smem[36864];   // 32KB staging + sRed slack

    // XCD swizzle: all 16 blocks of a bh land on one XCD (flat%8 == bh%8)
    const int flat = blockIdx.x;               // 0..511
    const int qt = (flat >> 3) & 15;           // 16 q-tiles of 128 rows
    const int bh = ((flat >> 7) << 3) | (flat & 7);
    const int b = bh >> 4, h = bh & 15;
    const _Float16* __restrict__ Qp = Qg + (size_t)bh * QLEN * DPH;
    const _Float16* __restrict__ Kp = Kg + (size_t)bh * QLEN * DPH;
    const _Float16* __restrict__ Vp = Vg + (size_t)bh * DPH * QLEN;

    const int tid = threadIdx.x, w = tid >> 6, l = tid & 63;
    const int qsub = w & 3, ksplit = w >> 2;
    const int ln = l & 31, hi = l >> 5;
    const int q0 = qt * 128 + qsub * 32;
    const int kbase = ksplit * 1024;           // this half's 1024 keys

    // LDS (halves): K pool [ksplit][buf][1024 keys-rows..]: 32x64 = 2048 h
    //               V pool base 8192 h: [ksplit][buf][64x32] = 2048 h
    _Float16* sK0 = (_Float16*)smem + ksplit * 4096;          // buf1 = +2048
    _Float16* sV0 = (_Float16*)smem + 8192 + ksplit * 4096;   // buf1 = +2048

    // Q B-frags (4 k-steps over d=64), direct from global
    half8 qf[4];
#pragma unroll
    for (int ks = 0; ks < 4; ++ks)
        qf[ks] = *(const half8*)&Qp[(size_t)(q0 + ln) * DPH + ks * 16 + hi * 8];

    f32x16 accT[2] = {};
    float lsum = 0.f;

    // ---- hoisted LDS read pointers (XOR-swizzled) ----
    // K tile [32 keys][64 d] (128B rows): pos = (ks*2+hi) ^ (row&7), row = ln
    const _Float16* kptr[4];
#pragma unroll
    for (int ks = 0; ks < 4; ++ks)
        kptr[ks] = sK0 + ln * 64 + (((ks * 2 + hi) ^ (ln & 7)) * 8);
    // V tile [64 d][32 keys] (64B rows): pos = (k2*2+hi) ^ ((row>>1)&3)
    const _Float16* vptr[2][2];
#pragma unroll
    for (int dblk = 0; dblk < 2; ++dblk)
#pragma unroll
        for (int k2 = 0; k2 < 2; ++k2)
            vptr[dblk][k2] = sV0 + (dblk * 32 + ln) * 32 +
                             (((k2 * 2 + hi) ^ ((ln >> 1) & 3)) * 8);

    // ---- hoisted stage pointers (strength-reduced per tile) ----
    // K: wave stages rows qsub*8 + (l>>3), chunk (l&7)^(l>>3)  (8 chunks/row)
    // V: wave stages rows qsub*16 + (l>>2), chunk (l&3)^((l>>3)&3) (4/row)
    const int c8k = ((l & 7) ^ (l >> 3)) * 8;
    const int c8v = ((l & 3) ^ ((l >> 3) & 3)) * 8;
    const _Float16* gK = &Kp[(size_t)(kbase + qsub * 8 + (l >> 3)) * DPH + c8k];
    const _Float16* gV = &Vp[(size_t)(qsub * 16 + (l >> 2)) * QLEN + kbase + c8v];
    _Float16* dK = sK0 + (qsub * 8) * 64 + l * 8;
    _Float16* dV = sV0 + (qsub * 16) * 32 + l * 8;

    auto stageAdv = [&](int bb) {
        gload_lds16(gK, dK + bb * 2048);
        gload_lds16(gV, dV + bb * 2048);
        gK += 32 * DPH;                        // next 32-key tile of K
        gV += 32;                              // next 32 keys along V^T row
    };

    auto compute = [&](int bb) {
        const int boff = bb * 2048;
        // S^T tile (32 keys x 32 q), full d=64 contraction
        f32x16 st = {};
        __builtin_amdgcn_s_setprio(1);
#pragma unroll
        for (int ks = 0; ks < 4; ++ks) {
            half8 kf = *(const half8*)(kptr[ks] + boff);
            st = __builtin_amdgcn_mfma_f32_32x32x16_f16(kf, qf[ks], st, 0, 0, 0);
        }
        __builtin_amdgcn_s_setprio(0);

        // p = 2^s (log2e folded into Q; masked K rows zero -> p = 1)
        int cpk[8];
#pragma unroll
        for (int i = 0; i < 8; ++i) {
            float e0 = __builtin_amdgcn_exp2f(st[2 * i]);
            float e1 = __builtin_amdgcn_exp2f(st[2 * i + 1]);
            lsum += e0 + e1;
            cpk[i] = __builtin_bit_cast(int, __builtin_amdgcn_cvt_pkrtz(e0, e1));
        }
        // D-layout -> B-frag repack: one permlane32_swap per dword pair
        asm("v_permlane32_swap_b32 %0, %1" : "+v"(cpk[0]), "+v"(cpk[2]));
        asm("v_permlane32_swap_b32 %0, %1" : "+v"(cpk[1]), "+v"(cpk[3]));
        asm("v_permlane32_swap_b32 %0, %1" : "+v"(cpk[4]), "+v"(cpk[6]));
        asm("v_permlane32_swap_b32 %0, %1" : "+v"(cpk[5]), "+v"(cpk[7]));
        int4v b0 = {cpk[0], cpk[1], cpk[2], cpk[3]};
        int4v b1 = {cpk[4], cpk[5], cpk[6], cpk[7]};
        half8 Bf0 = __builtin_bit_cast(half8, b0);   // keys 0..15
        half8 Bf1 = __builtin_bit_cast(half8, b1);   // keys 16..31

        // O^T += V^T P^T
        __builtin_amdgcn_s_setprio(1);
#pragma unroll
        for (int dblk = 0; dblk < 2; ++dblk) {
            half8 vf0 = *(const half8*)(vptr[dblk][0] + boff);
            half8 vf1 = *(const half8*)(vptr[dblk][1] + boff);
            accT[dblk] = __builtin_amdgcn_mfma_f32_32x32x16_f16(
                vf0, Bf0, accT[dblk], 0, 0, 0);
            accT[dblk] = __builtin_amdgcn_mfma_f32_32x32x16_f16(
                vf1, Bf1, accT[dblk], 0, 0, 0);
        }
        __builtin_amdgcn_s_setprio(0);
    };

    // ---- main loop: 32 tiles of 32 keys, unrolled x2, counted vmcnt ----
    stageAdv(0);                   // tile 0 -> buf0 (2 in flight)
    for (int t = 0; t < 16; ++t) {
        stageAdv(1);               // tile 2t+1 -> buf1
        WAITB(2);                  // tile 2t landed; 2t+1 stays in flight
        compute(0);
        ENDB();
        stageAdv(0);               // tile 2t+2 -> buf0 (t=15: dummy, ws-safe)
        WAITB(2);
        compute(1);
        ENDB();
    }
    // drain dummy tail-stage (its LDS writes alias the sRed region below)
    asm volatile("s_waitcnt vmcnt(0)" ::: "memory");
    __builtin_amdgcn_s_barrier();

    // own-wave hi-half merge (keys split by hi within the wave)
    lsum += __shfl_xor(lsum, 32);

    // ---- cross-wave key-split combine via LDS (aliased over staging) ----
    float* sRed = (float*)smem;                 // [4][64][33] = 33792 B
    if (ksplit == 1) {
        float* p = sRed + (qsub * 64 + l) * 33;
#pragma unroll
        for (int dblk = 0; dblk < 2; ++dblk)
#pragma unroll
            for (int i = 0; i < 16; ++i)
                p[dblk * 16 + i] = accT[dblk][i];
        p[32] = lsum;
    }
    __syncthreads();
    if (ksplit == 1) return;

    const float* p = sRed + (qsub * 64 + l) * 33;
#pragma unroll
    for (int dblk = 0; dblk < 2; ++dblk)
#pragma unroll
        for (int i = 0; i < 16; ++i)
            accT[dblk][i] += p[dblk * 16 + i];
    lsum += p[32];

    const float inv = 1.f / lsum;
    _Float16* cp = ctx + ((size_t)(b * QLEN) + q0 + ln) * DIM + h * DPH;
#pragma unroll
    for (int dblk = 0; dblk < 2; ++dblk)
#pragma unroll
        for (int j = 0; j < 4; ++j) {
            half4 o4;
#pragma unroll
            for (int e = 0; e < 4; ++e)
                o4[e] = (_Float16)(accT[dblk][4 * j + e] * inv);
            *(half4*)&cp[dblk * 32 + 8 * j + 4 * hi] = o4;
        }
}

// ---------------------------------------------------------------------------
extern "C" void kernel_launch(void* const* d_in, const int* in_sizes, int n_in,
                              void* d_out, int out_size, void* d_ws, size_t ws_size,
                              hipStream_t stream) {
    const float* x  = (const float*)d_in[0];
    const int* mask = (const int*)d_in[1];
    const float* Wq = (const float*)d_in[2];
    const float* bq = (const float*)d_in[3];
    const float* Wk = (const float*)d_in[4];
    const float* bk = (const float*)d_in[5];
    const float* Wv = (const float*)d_in[6];
    const float* bv = (const float*)d_in[7];
    const float* Wo = (const float*)d_in[8];
    const float* bo = (const float*)d_in[9];
    float* out = (float*)d_out;

    char* ws = (char*)d_ws;
    const size_t MB = 1u << 20;
    _Float16* X16  = (_Float16*)(ws + 0);
    _Float16* Wq16 = (_Float16*)(ws + 8 * MB);
    _Float16* Wk16 = (_Float16*)(ws + 10 * MB);
    _Float16* Wv16 = (_Float16*)(ws + 12 * MB);
    _Float16* Wo16 = (_Float16*)(ws + 14 * MB);
    _Float16* Q16  = (_Float16*)(ws + 16 * MB);  // [b][h][t][d], pre-scaled
    _Float16* K16  = (_Float16*)(ws + 24 * MB);  // [b][h][t][d], mask-zeroed
    _Float16* V16T = (_Float16*)(ws + 32 * MB);  // [b][h][d][t]
    _Float16* CTX  = (_Float16*)(ws + 40 * MB);  // [bt][dim]

    cvt_all<<<2048, 256, 0, stream>>>(x, Wq, Wk, Wv, Wo,
                                      X16, Wq16, Wk16, Wv16, Wo16);

    gemm_qkv<<<768, 256, 0, stream>>>(
        X16, Wq16, Wk16, Wv16, bq, bk, bv, mask, Q16, K16, V16T);

    attn_kernel<<<512, 512, 0, stream>>>(Q16, K16, V16T, CTX);

    gemm_out<<<dim3(8, 64), 256, 0, stream>>>(CTX, Wo16, bo, out);
}

// Round 21
// 114.026 us; speedup vs baseline: 1.0033x; 1.0033x over previous
//
#include <hip/hip_runtime.h>

typedef __attribute__((ext_vector_type(8))) _Float16 half8;
typedef __attribute__((ext_vector_type(4))) _Float16 half4;
typedef __attribute__((ext_vector_type(4))) float f32x4;
typedef __attribute__((ext_vector_type(16))) float f32x16;
typedef __attribute__((ext_vector_type(4))) int int4v;

#define BS 2
#define QLEN 2048
#define DIM 1024
#define NH 16
#define DPH 64
#define MTOT (BS * QLEN)   // 4096
#define LOG2E 1.44269504088896340736f

// counted-vmcnt barrier pair (T4): publish LDS without draining in-flight
// prefetch loads. WAITB: own prev-tile loads done -> barrier -> pin sched.
#define WAITB(N)                                          \
    asm volatile("s_waitcnt vmcnt(" #N ")" ::: "memory"); \
    __builtin_amdgcn_s_barrier();                         \
    __builtin_amdgcn_sched_barrier(0)
#define ENDB()                                            \
    __builtin_amdgcn_sched_barrier(0);                    \
    __builtin_amdgcn_s_barrier()

// ---------------------------------------------------------------------------
// merged fp32 -> fp16 conversion: X then Wq/Wk/Wv/Wo in one grid-stride kernel
// ---------------------------------------------------------------------------
__global__ void cvt_all(const float* __restrict__ x,
                        const float* __restrict__ wq, const float* __restrict__ wk,
                        const float* __restrict__ wv, const float* __restrict__ wo,
                        _Float16* __restrict__ X16,
                        _Float16* __restrict__ Wq16, _Float16* __restrict__ Wk16,
                        _Float16* __restrict__ Wv16, _Float16* __restrict__ Wo16) {
    const int NX = (MTOT * DIM) / 4;        // 1,048,576 float4
    const int NW = (DIM * DIM) / 4;         // 262,144 float4 (pow2 -> shifts)
    const int total = NX + 4 * NW;
    int idx = blockIdx.x * blockDim.x + threadIdx.x;
    int stride = gridDim.x * blockDim.x;
    for (int i = idx; i < total; i += stride) {
        const float* src; _Float16* dst; int off;
        if (i < NX) { src = x; dst = X16; off = i; }
        else {
            int k = i - NX; int which = k / NW; off = k - which * NW;
            src = which == 0 ? wq : which == 1 ? wk : which == 2 ? wv : wo;
            dst = which == 0 ? Wq16 : which == 1 ? Wk16 : which == 2 ? Wv16 : Wo16;
        }
        float4 v = ((const float4*)src)[off];
        half4 o;
        o[0] = (_Float16)v.x; o[1] = (_Float16)v.y;
        o[2] = (_Float16)v.z; o[3] = (_Float16)v.w;
        ((half4*)dst)[off] = o;
    }
}

// ---------------------------------------------------------------------------
__device__ __forceinline__ void gload_lds16(const _Float16* g, _Float16* l) {
    __builtin_amdgcn_global_load_lds(
        (const __attribute__((address_space(1))) void*)g,
        (__attribute__((address_space(3))) void*)l, 16, 0, 0);
}

// ---------------------------------------------------------------------------
// Fused QKV NT-GEMM (R16 best-measured): 128x128 tile, 2-phase dbuf,
// counted-vmcnt raw barriers, 4-chunk XOR swizzle, hoisted pointers, XCD
// grid, LDS-repack coalesced epilogue (z=2 transposed in LDS).
// z=0: Q16 scaled by (1/8)*log2e; z=1: K16 mask-zeroed; z=2: V16T.
// ---------------------------------------------------------------------------
__global__ __launch_bounds__(256) void gemm_qkv(
    const _Float16* __restrict__ A,
    const _Float16* __restrict__ Wq, const _Float16* __restrict__ Wk,
    const _Float16* __restrict__ Wv,
    const float* __restrict__ bq, const float* __restrict__ bk,
    const float* __restrict__ bv, const int* __restrict__ mask,
    _Float16* __restrict__ Qd, _Float16* __restrict__ Kd,
    _Float16* __restrict__ Vd) {
    const int K = 1024;
    // one flat LDS pool: sA[bb] = sm + bb*4096, sB[bb] = sm + 8192 + bb*4096.
    // Epilogue reuses all 16384 halves as the 128x128 output tile.
    __shared__ _Float16 sm[16384];

    // XCD-aware decode (bijective; per-XCD WS ~ L2-resident)
    const int flat = blockIdx.x;             // 0..767
    const int xcd = flat & 7, seq = flat >> 3;
    const int ya = xcd >> 1, nb = xcd & 1;
    const int n_hi = seq & 3;
    const int rem = seq >> 2;                // 0..23
    const int z = rem % 3, y_hi = rem / 3;   // y_hi 0..7
    const int y = y_hi * 4 + ya;             // 0..31
    const int nblk = n_hi * 2 + nb;          // 0..7
    const int m0 = y * 128, n0 = nblk * 128;

    const _Float16* W = (z == 0) ? Wq : (z == 1) ? Wk : Wv;
    const float* bias = (z == 0) ? bq : (z == 1) ? bk : bv;

    const int tid = threadIdx.x, w = tid >> 6, l = tid & 63;
    const int wr = (w >> 1) * 64, wc = (w & 1) * 64;
    const int r = l & 15, g = l >> 4;

    // hoisted stage pointers: slot s = tid + i*256 holds chunk (s&3)^(row&3)
    const _Float16* gA[2];
    const _Float16* gW[2];
    _Float16* dA[2];
    _Float16* dB[2];
#pragma unroll
    for (int i = 0; i < 2; ++i) {
        int s = tid + i * 256, row = s >> 2, pos = s & 3;
        int chunk = pos ^ (row & 3);
        gA[i] = &A[(size_t)(m0 + row) * K + chunk * 8];
        gW[i] = &W[(size_t)(n0 + row) * K + chunk * 8];
        dA[i] = &sm[s * 8];
        dB[i] = &sm[8192 + s * 8];
    }
    auto stageAdv = [&](int bb) {
#pragma unroll
        for (int i = 0; i < 2; ++i) {
            gload_lds16(gA[i], dA[i] + bb * 4096);
            gload_lds16(gW[i], dB[i] + bb * 4096);
            gA[i] += 32;                      // next BK=32 K-slice
            gW[i] += 32;
        }
    };

    // hoisted frag pointers; swizzled read pos = g ^ (r&3) (row-invariant)
    const int fpos = (g ^ (r & 3)) * 8;
    const _Float16* pA[4];
    const _Float16* pB[4];
#pragma unroll
    for (int i = 0; i < 4; ++i) {
        pA[i] = &sm[(wr + i * 16 + r) * 32] + fpos;
        pB[i] = &sm[8192 + (wc + i * 16 + r) * 32] + fpos;
    }

    f32x4 acc[4][4] = {};
    auto compute = [&](int bb) {
        const int boff = bb * 4096;
        half8 af[4], bf[4];
#pragma unroll
        for (int i = 0; i < 4; ++i) {
            af[i] = *(const half8*)(pA[i] + boff);
            bf[i] = *(const half8*)(pB[i] + boff);
        }
#pragma unroll
        for (int i = 0; i < 4; ++i)
#pragma unroll
            for (int j = 0; j < 4; ++j)
                acc[i][j] = __builtin_amdgcn_mfma_f32_16x16x32_f16(
                    af[i], bf[j], acc[i][j], 0, 0, 0);
    };

    // ---- main loop: 32 K-steps, unrolled x2, counted-vmcnt pipeline ----
    stageAdv(0);                 // k0 -> buf0          (4 in flight)
    for (int t = 0; t < 16; ++t) {
        stageAdv(1);             // k(2t+1) -> buf1     (8 in flight)
        WAITB(4);                // k(2t) landed; k(2t+1) stays in flight
        compute(0);
        ENDB();                  // all waves done reading buf0
        stageAdv(0);             // k(2t+2) -> buf0 (t=15: dummy, ws-safe)
        WAITB(4);                // k(2t+1) landed
        compute(1);
        ENDB();
    }
    // drain the dummy tail-stage before reusing LDS for the epilogue
    asm volatile("s_waitcnt vmcnt(0)" ::: "memory");
    __builtin_amdgcn_s_barrier();

    float bv4[4];
#pragma unroll
    for (int j = 0; j < 4; ++j) bv4[j] = bias[n0 + wc + j * 16 + r];

    // ---- epilogue pass 1: acc -> LDS, destination-major, chunk-swizzled ----
    if (z != 2) {
        // [m=tt_local][n=d-span]; chunk-XOR (n>>3)^(m&15) spreads banks
#pragma unroll
        for (int i = 0; i < 4; ++i)
#pragma unroll
            for (int j = 0; j < 4; ++j)
#pragma unroll
                for (int reg = 0; reg < 4; ++reg) {
                    const int m = wr + i * 16 + g * 4 + reg;
                    const int n = wc + j * 16 + r;
                    float v = acc[i][j][reg] + bv4[j];
                    if (z == 0) v *= 0.125f * LOG2E;
                    sm[m * 128 + (((n >> 3) ^ (m & 15)) * 8) + (n & 7)] =
                        (_Float16)v;
                }
    } else {
        // transposed: [n=d_local][m=tt-span]
#pragma unroll
        for (int i = 0; i < 4; ++i)
#pragma unroll
            for (int j = 0; j < 4; ++j)
#pragma unroll
                for (int reg = 0; reg < 4; ++reg) {
                    const int m = wr + i * 16 + g * 4 + reg;
                    const int n = wc + j * 16 + r;
                    float v = acc[i][j][reg] + bv4[j];
                    sm[n * 128 + (((m >> 3) ^ (n & 15)) * 8) + (m & 7)] =
                        (_Float16)v;
                }
    }
    __syncthreads();

    // ---- epilogue pass 2: 8 coalesced half8 stores per thread ----
    const int bb = m0 >> 11;                    // uniform per block
    if (z != 2) {
        _Float16* dst0 = (z == 0) ? Qd : Kd;
        const half8 zz = {};
#pragma unroll
        for (int k = 0; k < 8; ++k) {
            const int c = tid * 8 + k;          // 0..2047
            const int m = c >> 4, cc = c & 15;
            half8 v = *(const half8*)&sm[m * 128 + ((cc ^ (m & 15)) * 8)];
            const int ttl = (m0 + m) & 2047;
            const int h = (n0 >> 6) + (cc >> 3);
            const int d = (cc & 7) * 8;
            if (z == 1 && mask[bb * QLEN + ttl] == 0) v = zz;
            *(half8*)&dst0[(((size_t)(bb * NH + h)) * QLEN + ttl) * DPH + d] = v;
        }
    } else {
#pragma unroll
        for (int k = 0; k < 8; ++k) {
            const int c = tid * 8 + k;
            const int dl = c >> 4, cc = c & 15;
            half8 v = *(const half8*)&sm[dl * 128 + ((cc ^ (dl & 15)) * 8)];
            const int ng = n0 + dl, h = ng >> 6, dg = ng & 63;
            const int tt0 = (m0 & 2047) + cc * 8;
            *(half8*)&Vd[(((size_t)(bb * NH + h)) * DPH + dg) * QLEN + tt0] = v;
        }
    }
}

// ---------------------------------------------------------------------------
// Output GEMM: out = CTX @ Wo^T + bo (fp32). 64x128 tile + hoisted pointers
// + unroll x2 + counted-vmcnt raw barriers (R13 exact — frozen).
// ---------------------------------------------------------------------------
__global__ __launch_bounds__(256) void gemm_out(
    const _Float16* __restrict__ A, const _Float16* __restrict__ W,
    const float* __restrict__ bias, float* __restrict__ out) {
    const int K = 1024;
    __shared__ _Float16 sA[2][64 * 32];
    __shared__ _Float16 sB[2][128 * 32];
    const int m0 = blockIdx.y * 64, n0 = blockIdx.x * 128;
    const int tid = threadIdx.x, w = tid >> 6, l = tid & 63;
    const int wr = (w >> 1) * 32, wc = (w & 1) * 64;
    const int r = l & 15, g = l >> 4;

    // hoisted stage pointers (linear layout)
    const _Float16* gA;
    const _Float16* gB[2];
    _Float16* dA;
    _Float16* dB[2];
    {
        int s = tid, row = s >> 2, seg = (s & 3) * 8;
        gA = &A[(size_t)(m0 + row) * K + seg];
        dA = &sA[0][s * 8];
    }
#pragma unroll
    for (int i = 0; i < 2; ++i) {
        int s = tid + i * 256, row = s >> 2, seg = (s & 3) * 8;
        gB[i] = &W[(size_t)(n0 + row) * K + seg];
        dB[i] = &sB[0][s * 8];
    }
    auto stageAdv = [&](int bb) {
        gload_lds16(gA, dA + bb * 2048);
        gA += 32;
#pragma unroll
        for (int i = 0; i < 2; ++i) {
            gload_lds16(gB[i], dB[i] + bb * 4096);
            gB[i] += 32;
        }
    };

    const _Float16* pA[2];
    const _Float16* pB[4];
#pragma unroll
    for (int i = 0; i < 2; ++i)
        pA[i] = &sA[0][(wr + i * 16 + r) * 32 + g * 8];
#pragma unroll
    for (int j = 0; j < 4; ++j)
        pB[j] = &sB[0][(wc + j * 16 + r) * 32 + g * 8];

    f32x4 acc[2][4] = {};
    auto compute = [&](int bb) {
        half8 af[2], bf[4];
#pragma unroll
        for (int i = 0; i < 2; ++i)
            af[i] = *(const half8*)(pA[i] + bb * 2048);
#pragma unroll
        for (int j = 0; j < 4; ++j)
            bf[j] = *(const half8*)(pB[j] + bb * 4096);
#pragma unroll
        for (int i = 0; i < 2; ++i)
#pragma unroll
            for (int j = 0; j < 4; ++j)
                acc[i][j] = __builtin_amdgcn_mfma_f32_16x16x32_f16(
                    af[i], bf[j], acc[i][j], 0, 0, 0);
    };

    stageAdv(0);
    for (int t = 0; t < 16; ++t) {
        stageAdv(1);
        WAITB(3);
        compute(0);
        ENDB();
        stageAdv(0);             // t=15: dummy, ws-safe
        WAITB(3);
        compute(1);
        ENDB();
    }

    float bv4[4];
#pragma unroll
    for (int j = 0; j < 4; ++j) bv4[j] = bias[n0 + wc + j * 16 + r];
#pragma unroll
    for (int i = 0; i < 2; ++i)
#pragma unroll
        for (int j = 0; j < 4; ++j) {
            const int n = n0 + wc + j * 16 + r;
#pragma unroll
            for (int reg = 0; reg < 4; ++reg) {
                const int m = m0 + wr + i * 16 + g * 4 + reg;
                out[(size_t)m * DIM + n] = acc[i][j][reg] + bv4[j];
            }
        }
}

// ---------------------------------------------------------------------------
// Flash attention v7 (R15/R16/R19 exact — best measured).
// ---------------------------------------------------------------------------
__global__ __launch_bounds__(512) void attn_kernel(
    const _Float16* __restrict__ Qg, const _Float16* __restrict__ Kg,
    const _Float16* __restrict__ Vg, _Float16* __restrict__ ctx) {
    __shared__ __align__(16) char smem[65536];

    // XCD swizzle: all 16 blocks of a bh land on one XCD (flat%8 == bh%8)
    const int flat = blockIdx.x;               // 0..511
    const int qt = (flat >> 3) & 15;           // 16 q-tiles of 128 rows
    const int bh = ((flat >> 7) << 3) | (flat & 7);
    const int b = bh >> 4, h = bh & 15;
    const _Float16* __restrict__ Qp = Qg + (size_t)bh * QLEN * DPH;
    const _Float16* __restrict__ Kp = Kg + (size_t)bh * QLEN * DPH;
    const _Float16* __restrict__ Vp = Vg + (size_t)bh * DPH * QLEN;

    const int tid = threadIdx.x, w = tid >> 6, l = tid & 63;
    const int qsub = w & 3, ksplit = w >> 2;
    const int ln = l & 31, hi = l >> 5;
    const int q0 = qt * 128 + qsub * 32;
    const int kbase = ksplit * 1024;           // this half's 1024 keys

    // this ksplit's LDS bases, buffer 0 (buf1 = +4096 halves = 8192 B)
    _Float16* sK0 = (_Float16*)(smem + ksplit * 2 * 8192);
    _Float16* sV0 = (_Float16*)(smem + 32768 + ksplit * 2 * 8192);

    // Q B-frags (4 k-steps over d=64), direct from global
    half8 qf[4];
#pragma unroll
    for (int ks = 0; ks < 4; ++ks)
        qf[ks] = *(const half8*)&Qp[(size_t)(q0 + ln) * DPH + ks * 16 + hi * 8];

    f32x16 accT[2] = {};
    float lsum = 0.f;

    // ---- hoisted loop-invariant LDS read pointers (XOR-swizzled) ----
    const _Float16* kptr[2][4];
    const _Float16* vptr[2][2][2];
#pragma unroll
    for (int kb = 0; kb < 2; ++kb) {
#pragma unroll
        for (int ks = 0; ks < 4; ++ks)
            kptr[kb][ks] = sK0 + (kb * 32 + ln) * 64 + ((ks * 2 + hi) ^ (ln & 7)) * 8;
#pragma unroll
        for (int dblk = 0; dblk < 2; ++dblk) {
            vptr[kb][dblk][0] =
                sV0 + (dblk * 32 + ln) * 64 + ((kb * 4 + 0 + hi) ^ (ln & 7)) * 8;
            vptr[kb][dblk][1] =
                sV0 + (dblk * 32 + ln) * 64 + ((kb * 4 + 2 + hi) ^ (ln & 7)) * 8;
        }
    }

    // ---- hoisted stage pointers (strength-reduced per tile) ----
    const int c8 = ((l & 7) ^ (l >> 3)) * 8;   // pre-swizzled source chunk
    const int rl = l >> 3;
    const _Float16* gK[2];
    const _Float16* gV[2];
    _Float16* dK[2];
    _Float16* dV[2];
#pragma unroll
    for (int j = 0; j < 2; ++j) {
        const int r0 = qsub * 16 + j * 8;
        gK[j] = &Kp[(size_t)(kbase + r0 + rl) * DPH + c8];
        gV[j] = &Vp[(size_t)(r0 + rl) * QLEN + kbase + c8];
        dK[j] = sK0 + r0 * 64 + l * 8;
        dV[j] = sV0 + r0 * 64 + l * 8;
    }

    // stage current tile into buf bb, then advance global pointers one tile
    auto stageAdv = [&](int bb) {
#pragma unroll
        for (int j = 0; j < 2; ++j) {
            gload_lds16(gK[j], dK[j] + bb * 4096);
            gload_lds16(gV[j], dV[j] + bb * 4096);
            gK[j] += 64 * DPH;                 // next 64-key tile of K
            gV[j] += 64;                       // next 64 keys along V^T row
        }
    };

    auto compute = [&](int bb) {
        const int boff = bb * 4096;
#pragma unroll
        for (int kb = 0; kb < 2; ++kb) {
            // S^T tile (32 keys x 32 q)
            f32x16 st = {};
            __builtin_amdgcn_s_setprio(1);
#pragma unroll
            for (int ks = 0; ks < 4; ++ks) {
                half8 kf = *(const half8*)(kptr[kb][ks] + boff);
                st = __builtin_amdgcn_mfma_f32_32x32x16_f16(kf, qf[ks], st, 0, 0, 0);
            }
            __builtin_amdgcn_s_setprio(0);

            // p = 2^s (log2e folded into Q; masked K rows zero -> p = 1)
            int cpk[8];
#pragma unroll
            for (int i = 0; i < 8; ++i) {
                float e0 = __builtin_amdgcn_exp2f(st[2 * i]);
                float e1 = __builtin_amdgcn_exp2f(st[2 * i + 1]);
                lsum += e0 + e1;
                cpk[i] =
                    __builtin_bit_cast(int, __builtin_amdgcn_cvt_pkrtz(e0, e1));
            }
            // D-layout -> B-frag repack: one permlane32_swap per dword pair
            asm("v_permlane32_swap_b32 %0, %1" : "+v"(cpk[0]), "+v"(cpk[2]));
            asm("v_permlane32_swap_b32 %0, %1" : "+v"(cpk[1]), "+v"(cpk[3]));
            asm("v_permlane32_swap_b32 %0, %1" : "+v"(cpk[4]), "+v"(cpk[6]));
            asm("v_permlane32_swap_b32 %0, %1" : "+v"(cpk[5]), "+v"(cpk[7]));
            int4v b0 = {cpk[0], cpk[1], cpk[2], cpk[3]};
            int4v b1 = {cpk[4], cpk[5], cpk[6], cpk[7]};
            half8 Bf0 = __builtin_bit_cast(half8, b0);
            half8 Bf1 = __builtin_bit_cast(half8, b1);

            // O^T += V^T P^T
            __builtin_amdgcn_s_setprio(1);
#pragma unroll
            for (int dblk = 0; dblk < 2; ++dblk) {
                half8 vf0 = *(const half8*)(vptr[kb][dblk][0] + boff);
                half8 vf1 = *(const half8*)(vptr[kb][dblk][1] + boff);
                accT[dblk] = __builtin_amdgcn_mfma_f32_32x32x16_f16(
                    vf0, Bf0, accT[dblk], 0, 0, 0);
                accT[dblk] = __builtin_amdgcn_mfma_f32_32x32x16_f16(
                    vf1, Bf1, accT[dblk], 0, 0, 0);
            }
            __builtin_amdgcn_s_setprio(0);
        }
    };

    // ---- main loop: 16 tiles, unrolled x2, counted-vmcnt pipeline (T4) ----
    stageAdv(0);                   // tile 0 -> buf0 (4 in flight)
    for (int t = 0; t < 8; ++t) {
        stageAdv(1);               // tile 2t+1 -> buf1
        WAITB(4);                  // tile 2t landed (all waves); 2t+1 in flight
        compute(0);                // consume tile 2t
        ENDB();                    // all waves done reading buf0
        stageAdv(0);               // tile 2t+2 -> buf0 (t=7: dummy, ws-safe)
        WAITB(4);                  // tile 2t+1 landed
        compute(1);                // consume tile 2t+1
        ENDB();
    }
    // drain dummy tail-stage (its LDS writes alias the sRed region below)
    asm volatile("s_waitcnt vmcnt(0)" ::: "memory");
    __builtin_amdgcn_s_barrier();

    // own-wave hi-half merge (keys split by hi within the wave)
    lsum += __shfl_xor(lsum, 32);

    // ---- cross-wave key-split combine via LDS (aliased over staging) ----
    float* sRed = (float*)smem;                 // [4][64][33]
    if (ksplit == 1) {
        float* p = sRed + (qsub * 64 + l) * 33;
#pragma unroll
        for (int dblk = 0; dblk < 2; ++dblk)
#pragma unroll
            for (int i = 0; i < 16; ++i)
                p[dblk * 16 + i] = accT[dblk][i];
        p[32] = lsum;
    }
    __syncthreads();
    if (ksplit == 1) return;

    const float* p = sRed + (qsub * 64 + l) * 33;
#pragma unroll
    for (int dblk = 0; dblk < 2; ++dblk)
#pragma unroll
        for (int i = 0; i < 16; ++i)
            accT[dblk][i] += p[dblk * 16 + i];
    lsum += p[32];

    const float inv = 1.f / lsum;
    _Float16* cp = ctx + ((size_t)(b * QLEN) + q0 + ln) * DIM + h * DPH;
#pragma unroll
    for (int dblk = 0; dblk < 2; ++dblk)
#pragma unroll
        for (int j = 0; j < 4; ++j) {
            half4 o4;
#pragma unroll
            for (int e = 0; e < 4; ++e)
                o4[e] = (_Float16)(accT[dblk][4 * j + e] * inv);
            *(half4*)&cp[dblk * 32 + 8 * j + 4 * hi] = o4;
        }
}

// ---------------------------------------------------------------------------
extern "C" void kernel_launch(void* const* d_in, const int* in_sizes, int n_in,
                              void* d_out, int out_size, void* d_ws, size_t ws_size,
                              hipStream_t stream) {
    const float* x  = (const float*)d_in[0];
    const int* mask = (const int*)d_in[1];
    const float* Wq = (const float*)d_in[2];
    const float* bq = (const float*)d_in[3];
    const float* Wk = (const float*)d_in[4];
    const float* bk = (const float*)d_in[5];
    const float* Wv = (const float*)d_in[6];
    const float* bv = (const float*)d_in[7];
    const float* Wo = (const float*)d_in[8];
    const float* bo = (const float*)d_in[9];
    float* out = (float*)d_out;

    char* ws = (char*)d_ws;
    const size_t MB = 1u << 20;
    _Float16* X16  = (_Float16*)(ws + 0);
    _Float16* Wq16 = (_Float16*)(ws + 8 * MB);
    _Float16* Wk16 = (_Float16*)(ws + 10 * MB);
    _Float16* Wv16 = (_Float16*)(ws + 12 * MB);
    _Float16* Wo16 = (_Float16*)(ws + 14 * MB);
    _Float16* Q16  = (_Float16*)(ws + 16 * MB);  // [b][h][t][d], pre-scaled
    _Float16* K16  = (_Float16*)(ws + 24 * MB);  // [b][h][t][d], mask-zeroed
    _Float16* V16T = (_Float16*)(ws + 32 * MB);  // [b][h][d][t]
    _Float16* CTX  = (_Float16*)(ws + 40 * MB);  // [bt][dim]

    cvt_all<<<2048, 256, 0, stream>>>(x, Wq, Wk, Wv, Wo,
                                      X16, Wq16, Wk16, Wv16, Wo16);

    gemm_qkv<<<768, 256, 0, stream>>>(
        X16, Wq16, Wk16, Wv16, bq, bk, bv, mask, Q16, K16, V16T);

    attn_kernel<<<512, 512, 0, stream>>>(Q16, K16, V16T, CTX);

    gemm_out<<<dim3(8, 64), 256, 0, stream>>>(CTX, Wo16, bo, out);
}